// Round 24
// baseline (117.751 us; speedup 1.0000x reference)
//
#include <hip/hip_runtime.h>
#include <hip/hip_bf16.h>

typedef unsigned short u16;
typedef unsigned int   u32;
typedef __attribute__((ext_vector_type(8))) short bf16x8;   // 8 bf16 = 4 VGPR (MFMA A/B frag)
typedef __attribute__((ext_vector_type(4))) float f32x4;    // MFMA C/D frag
typedef __attribute__((ext_vector_type(4))) u16   u16x4;

__device__ __forceinline__ u16 f2bf(float f) {              // RNE float->bf16
    u32 u = __float_as_uint(f);
    u32 r = (u + 0x7FFFu + ((u >> 16) & 1u)) >> 16;
    return (u16)r;
}
__device__ __forceinline__ float bf2f(u16 h) {
    return __uint_as_float(((u32)h) << 16);
}
// pack two f32 -> (bf16_b << 16) | bf16_a, RNE, via COMPILER-emitted v_cvt_pk_bf16_f32
// (hazard-safe consumer of TRANS results; inline-asm consumers corrupted — R6..R13).
__device__ __forceinline__ u32 pack2bf(float a, float b) {
    __hip_bfloat162 h2 = __float22bfloat162_rn(make_float2(a, b));  // x->low, y->high
    return *reinterpret_cast<u32*>(&h2);
}
// single v_exp_f32 (TRANS pipe); consumers must be compiler-generated VALU only.
__device__ __forceinline__ float fexp2(float x) {
    return __builtin_amdgcn_exp2f(x);
}

// async global->LDS, 16B per lane. LDS dest is wave-uniform base (HW adds lane*16).
__device__ __forceinline__ void gll16(const u16* g, u16* l) {
    __builtin_amdgcn_global_load_lds(
        (const __attribute__((address_space(1))) u32*)(const void*)g,
        (__attribute__((address_space(3))) u32*)(void*)l, 16, 0, 0);
}

// ---------------- fused prep: x->bf16, weight transpose, bias concat ------------------
__device__ __forceinline__ void wt_tile(const float* Wq, const float* Wk, const float* Wv,
                                        u16* Whi, int K, int bx, int by,
                                        float* tile /* [32][33] */) {
    int k0 = by * 32, n0 = bx * 32;
    int tx = threadIdx.x & 31, ty = threadIdx.x >> 5;   // ty in 0..7
#pragma unroll
    for (int i = 0; i < 4; i++) {
        int kk = k0 + ty + i * 8;
        int n  = n0 + tx;
        float v;
        if (n < 1024)      v = Wq[(size_t)kk * 1024 + n];
        else if (n < 1280) v = Wk[(size_t)kk * 256 + (n - 1024)];
        else               v = Wv[(size_t)kk * 256 + (n - 1280)];
        tile[(ty + i * 8) * 33 + tx] = v;
    }
    __syncthreads();
#pragma unroll
    for (int i = 0; i < 4; i++) {
        int nn = n0 + ty + i * 8;      // output row (n)
        int kk = k0 + tx;              // output col (k)
        Whi[(size_t)nn * K + kk] = f2bf(tile[tx * 33 + ty + i * 8]);
    }
}

__global__ __launch_bounds__(256) void prep_all(
    const float* __restrict__ x,
    const float* __restrict__ Wq, const float* __restrict__ Wk, const float* __restrict__ Wv,
    const float* __restrict__ Wo,
    const float* __restrict__ bq, const float* __restrict__ bk, const float* __restrict__ bv,
    u16* __restrict__ xhi, u16* __restrict__ Wqkvh,
    u16* __restrict__ Woh, float* __restrict__ bqkv) {
    __shared__ float tile[32 * 33];
    int blk = blockIdx.x;
    if (blk < 4096) {                          // x fp32 -> bf16 (4 elems/thread)
        int i = blk * 256 + threadIdx.x;
        f32x4 v = *(const f32x4*)(x + (size_t)i * 4);
        u16x4 h;
#pragma unroll
        for (int j = 0; j < 4; j++) h[j] = f2bf(v[j]);
        *(u16x4*)(xhi + (size_t)i * 4) = h;
    } else if (blk < 4096 + 1536) {            // Wqkv^T hi (48 x 32 tiles)
        int id = blk - 4096;
        wt_tile(Wq, Wk, Wv, Wqkvh, 1024, id % 48, id / 48, tile);
    } else if (blk < 4096 + 1536 + 1024) {     // Wo^T hi (32 x 32 tiles)
        int id = blk - (4096 + 1536);
        wt_tile(Wo, Wo, Wo, Woh, 1024, id % 32, id / 32, tile);
    } else {                                   // bias concat
#pragma unroll
        for (int base = 0; base < 1536; base += 256) {
            int i = base + threadIdx.x;
            bqkv[i] = (i < 1024) ? bq[i] : ((i < 1280) ? bk[i - 1024] : bv[i - 1280]);
        }
    }
}

// ---------------- GEMM, 2-phase pipelined staging, 8 waves, single-bf16 ---------------
// C[M][N] = A @ B^T + bias.  Bt[N][K].  Tile 128 x BN.
// BN=128: waves 2x... each wave 32x64 (2x4 MFMA/K-step, 6 ds_reads) — all 8 waves
//         stage A and B symmetrically (uniform vmcnt(2)).
// BN=64:  each wave 32x32 (2x2 MFMA); B staged by waves 0-3 (split vmcnt).
// MODE 0: write C fp32. MODE 1: fused QKV epilogue -> Qb(*0.125*log2e), Kb,
//         and V written DIRECTLY to Vtp (transposed + key-permuted).
template<int MODE, int BN>
__global__ __launch_bounds__(512) void gemm_2ph(
    const u16* __restrict__ Ahi, const u16* __restrict__ Bhi,
    const float* __restrict__ bias, float* __restrict__ C,
    u16* __restrict__ Qb, u16* __restrict__ Kb, u16* __restrict__ Vtp,
    int M, int N, int K) {
    constexpr int NSUB = BN / 32;                       // n-subtiles per wave (2 or 4)
    __shared__ __align__(16) u16 sA[2][128 * 32];
    __shared__ __align__(16) u16 sB[2][BN * 32];
    int tid = threadIdx.x;
    int lane = tid & 63;
    int wv = tid >> 6;                                  // 0..7
    int m0 = blockIdx.y * 128, n0 = blockIdx.x * BN;
    int wm = (wv >> 1) * 32, wn = (wv & 1) * (BN / 2);
    int lr = lane & 15, lg = lane >> 4;

    f32x4 acc[2][NSUB];
#pragma unroll
    for (int a = 0; a < 2; a++)
#pragma unroll
        for (int b = 0; b < NSUB; b++) acc[a][b] = (f32x4){0.f, 0.f, 0.f, 0.f};

    // A staging: wave wv covers rows wv*16..+15 (slot = lane: row lane>>2, chunk lane&3)
    int rl = wv * 16 + (lane >> 2);                     // 0..127
    int jl = (((lane & 3) ^ ((rl >> 1) & 3)) * 8);      // pre-swizzled source chunk
    size_t aoff = (size_t)(m0 + rl) * K + jl;
    // B staging: BN=128 -> all 8 waves cover rows 0..127; BN=64 -> waves 0-3, rows 0..63
    int brl = (BN == 128 ? wv * 16 : (wv & 3) * 16) + (lane >> 2);
    int bjl = (((lane & 3) ^ ((brl >> 1) & 3)) * 8);
    size_t boff = (size_t)(n0 + brl) * K + bjl;

    auto STAGE = [&](int buf, int k0) {
        gll16(Ahi + aoff + k0, &sA[buf][0] + wv * 512);
        if constexpr (BN == 128) {
            gll16(Bhi + boff + k0, &sB[buf][0] + wv * 512);
        } else {
            if (wv < 4) gll16(Bhi + boff + k0, &sB[buf][0] + (wv & 3) * 512);
        }
    };

    STAGE(0, 0);
    int nit = K >> 5;
    for (int it = 0; it < nit; ++it) {
        int cur = it & 1;
        if (it + 1 < nit) {
            STAGE(cur ^ 1, (it + 1) * 32);             // next tile in flight during compute
            if constexpr (BN == 128) {
                asm volatile("s_waitcnt vmcnt(2)" ::: "memory");
            } else {
                if (wv < 4) asm volatile("s_waitcnt vmcnt(2)" ::: "memory");
                else        asm volatile("s_waitcnt vmcnt(1)" ::: "memory");
            }
        } else {
            asm volatile("s_waitcnt vmcnt(0)" ::: "memory");
        }
        __builtin_amdgcn_s_barrier();
        asm volatile("" ::: "memory");

        bf16x8 af[2], bfr[NSUB];
#pragma unroll
        for (int ms = 0; ms < 2; ms++) {
            int row = wm + ms * 16 + lr;
            af[ms] = *(const bf16x8*)&sA[cur][row * 32 + (lg ^ ((row >> 1) & 3)) * 8];
        }
#pragma unroll
        for (int ns = 0; ns < NSUB; ns++) {
            int row = wn + ns * 16 + lr;
            bfr[ns] = *(const bf16x8*)&sB[cur][row * 32 + (lg ^ ((row >> 1) & 3)) * 8];
        }
        __builtin_amdgcn_s_setprio(1);
#pragma unroll
        for (int ms = 0; ms < 2; ms++)
#pragma unroll
            for (int ns = 0; ns < NSUB; ns++)
                acc[ms][ns] = __builtin_amdgcn_mfma_f32_16x16x32_bf16(af[ms], bfr[ns], acc[ms][ns], 0, 0, 0);
        __builtin_amdgcn_s_setprio(0);
        __builtin_amdgcn_s_barrier();   // all reads of cur done before it is restaged
    }

    int rq = lg * 4;
#pragma unroll
    for (int ns = 0; ns < NSUB; ns++) {
        int n = n0 + wn + ns * 16 + lr;
        float bvv = bias[n];
#pragma unroll
        for (int ms = 0; ms < 2; ms++) {
            int mbase = m0 + wm + ms * 16 + rq;
#pragma unroll
            for (int r = 0; r < 4; r++) {
                float val = acc[ms][ns][r] + bvv;
                int m = mbase + r;
                if (MODE == 0) {
                    C[(size_t)m * N + n] = val;
                } else {
                    if (n < 1024)      Qb[(size_t)m * 1024 + n] = f2bf(val * 0.1803368801f);
                    else if (n < 1280) Kb[(size_t)m * 256 + (n - 1024)] = f2bf(val);
                    else {
                        // direct transposed + key-permuted V write (replaces prep_vt):
                        // p(ti) inverts attn's ti(p)=((p&1)<<4)|((p>>1)&15)|(p&32)
                        int dh6 = n - 1280;                 // 0..255
                        int g = dh6 >> 6, dh = dh6 & 63;
                        int bb = m >> 11, tok = m & 2047;
                        int ti = tok & 63;
                        int p = ((ti >> 4) & 1) | ((ti & 15) << 1) | (ti & 32);
                        Vtp[((size_t)((bb * 4 + g) * 64 + dh)) * 2048 + (tok & ~63) + p]
                            = f2bf(val);
                    }
                }
            }
        }
    }
}

// ---------------- flash attention (R23-proven, ~67.5us — byte-identical) --------------
// 4 waves x 32 q-rows, 512 blocks; (b,g) in LOW 3 bid bits (XCD-local KV streams);
// triple-buffered K/V via global_load_lds, ONE barrier/iter; chunk-XOR swizzle;
// no-max exp2 softmax (Q pre-scaled by 0.125*log2e), deferred denominator;
// pack via v_cvt_pk (compiler); setprio around MFMA clusters; O single bf16.
__global__ __launch_bounds__(256) void attn_kernel(
    const u16* __restrict__ Qb, const u16* __restrict__ Kb,
    const u16* __restrict__ Vtp, u16* __restrict__ Ohi) {
    __shared__ __align__(16) u16 sK[3][4096];
    __shared__ __align__(16) u16 sV[3][4096];
    __shared__ __align__(16) u16 sP[4][32 * 72];

    const int tid = threadIdx.x;
    const int wv = tid >> 6, lane = tid & 63;
    const int lr = lane & 15, lg = lane >> 4;

    const int bid = blockIdx.x;
    const int b  = bid & 1;                  // (b,g) in LOW 3 bits -> XCD-local KV stream
    const int g  = (bid >> 1) & 3;
    const int h  = g * 4 + ((bid >> 3) & 3);
    const int tc = (bid >> 5) & 15;
    const int tok0 = tc * 128 + wv * 32;

    // Q A-fragments: 2 m-tiles x 2 k-steps
    bf16x8 qf[2][2];
#pragma unroll
    for (int mm = 0; mm < 2; mm++) {
        const u16* qrow = Qb + (size_t)(b * 2048 + tok0 + mm * 16 + lr) * 1024 + h * 64 + lg * 8;
        qf[mm][0] = *(const bf16x8*)(qrow);
        qf[mm][1] = *(const bf16x8*)(qrow + 32);
    }

    // staging: wave covers rows wv*16..+15 (2 issues of 8 rows), swizzled source chunk
    const int srow = wv * 16 + (lane >> 3);
    const int sjj  = (lane & 7) ^ (srow & 7);
    const u16* kgb = Kb  + (size_t)(b * 2048 + srow) * 256 + g * 64 + sjj * 8;
    const u16* vgb = Vtp + (size_t)((b * 4 + g) * 64 + srow) * 2048 + sjj * 8;

    f32x4 o_[2][4];
    float ls[2][4];
#pragma unroll
    for (int mm = 0; mm < 2; mm++)
#pragma unroll
        for (int r = 0; r < 4; r++) { o_[mm][r] = (f32x4){0.f, 0.f, 0.f, 0.f}; ls[mm][r] = 0.f; }

    // prologue: stage tile 0 into buffer 0
    gll16(kgb,         &sK[0][0] + wv * 1024);
    gll16(kgb + 2048,  &sK[0][0] + wv * 1024 + 512);
    gll16(vgb,         &sV[0][0] + wv * 1024);
    gll16(vgb + 16384, &sV[0][0] + wv * 1024 + 512);

    int bufn = 0;                        // buffer holding tile `it` (cycles 0,1,2)
    for (int it = 0; it < 32; ++it) {
        if (it < 31) {
            int nb = bufn + 1; if (nb == 3) nb = 0;
            const u16* kp = kgb + (size_t)(it + 1) * 16384;
            const u16* vp = vgb + (size_t)(it + 1) * 64;
            u16* kd = &sK[nb][0] + wv * 1024;
            u16* vd = &sV[nb][0] + wv * 1024;
            gll16(kp,         kd);
            gll16(kp + 2048,  kd + 512);
            gll16(vp,         vd);
            gll16(vp + 16384, vd + 512);
            asm volatile("s_waitcnt vmcnt(4)" ::: "memory");   // cur landed, next 4 in flight
        } else {
            asm volatile("s_waitcnt vmcnt(0)" ::: "memory");
        }
        __builtin_amdgcn_s_barrier();    // ONE barrier per iter (R19-proven ledger)

        const u16* kt = &sK[bufn][0];
        const u16* vt = &sV[bufn][0];

        // K fragments (shared across m-tiles)
        bf16x8 kf0[4], kf1[4];
#pragma unroll
        for (int t = 0; t < 4; t++) {
            int row = t * 16 + lr;
            kf0[t] = *(const bf16x8*)(kt + (row * 8 + (lg ^ (row & 7))) * 8);
            kf1[t] = *(const bf16x8*)(kt + (row * 8 + ((4 + lg) ^ (row & 7))) * 8);
        }
        // S = Q @ K^T (exp2 domain)
        f32x4 s[2][4];
        __builtin_amdgcn_s_setprio(1);
#pragma unroll
        for (int mm = 0; mm < 2; mm++)
#pragma unroll
            for (int t = 0; t < 4; t++) {
                f32x4 sc = (f32x4){0.f, 0.f, 0.f, 0.f};
                sc = __builtin_amdgcn_mfma_f32_16x16x32_bf16(qf[mm][0], kf0[t], sc, 0, 0, 0);
                sc = __builtin_amdgcn_mfma_f32_16x16x32_bf16(qf[mm][1], kf1[t], sc, 0, 0, 0);
                s[mm][t] = sc;
            }
        __builtin_amdgcn_s_setprio(0);

        // P = exp2(S); accumulate denominator per-lane; pack pairs -> LDS
        u16* sPw = &sP[wv][0];
#pragma unroll
        for (int mm = 0; mm < 2; mm++)
#pragma unroll
            for (int r = 0; r < 4; r++) {
                float p0 = fexp2(s[mm][0][r]);
                float p1 = fexp2(s[mm][1][r]);
                float p2 = fexp2(s[mm][2][r]);
                float p3 = fexp2(s[mm][3][r]);
                ls[mm][r] += (p0 + p1) + (p2 + p3);
                u32 w0 = pack2bf(p0, p1);        // positions 2lr,2lr+1 = keys lr,16+lr
                u32 w1 = pack2bf(p2, p3);        // positions 32+2lr,.. = keys 32+lr,48+lr
                int rowo = (mm * 16 + lg * 4 + r) * 72;
                *(u32*)(sPw + rowo + lr * 2)      = w0;
                *(u32*)(sPw + rowo + 32 + lr * 2) = w1;
            }
        asm volatile("s_waitcnt lgkmcnt(0)" ::: "memory");
        __builtin_amdgcn_sched_barrier(0);

        // O += P @ V  (V tile is key-permuted to match P's packed positions)
        __builtin_amdgcn_s_setprio(1);
#pragma unroll
        for (int ks = 0; ks < 2; ks++) {
            bf16x8 vf[4];
#pragma unroll
            for (int n = 0; n < 4; n++) {
                int row = n * 16 + lr;
                vf[n] = *(const bf16x8*)(vt + (row * 8 + ((ks * 4 + lg) ^ (row & 7))) * 8);
            }
#pragma unroll
            for (int mm = 0; mm < 2; mm++) {
                bf16x8 pa = *(const bf16x8*)(sPw + (mm * 16 + lr) * 72 + ks * 32 + lg * 8);
#pragma unroll
                for (int n = 0; n < 4; n++)
                    o_[mm][n] = __builtin_amdgcn_mfma_f32_16x16x32_bf16(pa, vf[n], o_[mm][n], 0, 0, 0);
            }
        }
        __builtin_amdgcn_s_setprio(0);
        bufn = bufn + 1; if (bufn == 3) bufn = 0;
    }

    // deferred denominator reduce + normalize + bf16 write (single term)
#pragma unroll
    for (int mm = 0; mm < 2; mm++)
#pragma unroll
        for (int r = 0; r < 4; r++) {
            float l = ls[mm][r];
#pragma unroll
            for (int off = 1; off < 16; off <<= 1) l += __shfl_xor(l, off, 64);
            float inv = 1.f / l;
            int row = b * 2048 + tok0 + mm * 16 + lg * 4 + r;
#pragma unroll
            for (int n = 0; n < 4; n++) {
                size_t idx = (size_t)row * 1024 + h * 64 + n * 16 + lr;
                Ohi[idx] = f2bf(o_[mm][n][r] * inv);
            }
        }
}

// ---------------- launch (4 dispatches) ----------------
extern "C" void kernel_launch(void* const* d_in, const int* in_sizes, int n_in,
                              void* d_out, int out_size, void* d_ws, size_t ws_size,
                              hipStream_t stream) {
    const float* x   = (const float*)d_in[0];
    const float* W_q = (const float*)d_in[1];
    const float* b_q = (const float*)d_in[2];
    const float* W_k = (const float*)d_in[3];
    const float* b_k = (const float*)d_in[4];
    const float* W_v = (const float*)d_in[5];
    const float* b_v = (const float*)d_in[6];
    const float* W_o = (const float*)d_in[7];
    const float* b_o = (const float*)d_in[8];
    float* out = (float*)d_out;

    char* ws = (char*)d_ws;
    u16*   xhi   = (u16*)(ws + 0);            //  8 MB  [4096][1024]
    u16*   Wqkvh = (u16*)(ws + 8388608);      //  3 MB  [1536][1024]
    float* bqkv  = (float*)(ws + 11534336);   //  6 KB
    u16*   Qb    = (u16*)(ws + 11540480);     //  8 MB  [4096][1024] (pre-scaled)
    u16*   Kb    = (u16*)(ws + 19929088);     //  2 MB  [4096][256]
    u16*   Vtp   = (u16*)(ws + 22026240);     //  2 MB  [8][64][2048] key-permuted
    u16*   Woh   = (u16*)(ws + 24123392);     //  2 MB  [1024][1024]
    u16*   Ahi   = (u16*)(ws + 26220544);     //  8 MB  attn-out bf16 (ends 34,609,152)

    prep_all<<<6657, 256, 0, stream>>>(x, W_q, W_k, W_v, W_o, b_q, b_k, b_v,
                                       xhi, Wqkvh, Woh, bqkv);
    gemm_2ph<1, 128><<<dim3(12, 32), 512, 0, stream>>>(xhi, Wqkvh, bqkv,
                                                       nullptr, Qb, Kb, Vtp, 4096, 1536, 1024);
    attn_kernel<<<512, 256, 0, stream>>>(Qb, Kb, Vtp, Ahi);
    gemm_2ph<0, 64><<<dim3(16, 32), 512, 0, stream>>>(Ahi, Woh, b_o, out,
                                                      nullptr, nullptr, nullptr, 4096, 1024, 1024);
}

// Round 25
// 115.538 us; speedup vs baseline: 1.0192x; 1.0192x over previous
//
#include <hip/hip_runtime.h>
#include <hip/hip_bf16.h>

typedef unsigned short u16;
typedef unsigned int   u32;
typedef __attribute__((ext_vector_type(8))) short bf16x8;   // 8 bf16 = 4 VGPR (MFMA A/B frag)
typedef __attribute__((ext_vector_type(4))) float f32x4;    // MFMA C/D frag
typedef __attribute__((ext_vector_type(4))) u16   u16x4;

__device__ __forceinline__ u16 f2bf(float f) {              // RNE float->bf16
    u32 u = __float_as_uint(f);
    u32 r = (u + 0x7FFFu + ((u >> 16) & 1u)) >> 16;
    return (u16)r;
}
__device__ __forceinline__ float bf2f(u16 h) {
    return __uint_as_float(((u32)h) << 16);
}
// pack two f32 -> (bf16_b << 16) | bf16_a, RNE, via COMPILER-emitted v_cvt_pk_bf16_f32
// (hazard-safe consumer of TRANS results; inline-asm consumers corrupted — R6..R13).
__device__ __forceinline__ u32 pack2bf(float a, float b) {
    __hip_bfloat162 h2 = __float22bfloat162_rn(make_float2(a, b));  // x->low, y->high
    return *reinterpret_cast<u32*>(&h2);
}
// single v_exp_f32 (TRANS pipe); consumers must be compiler-generated VALU only.
__device__ __forceinline__ float fexp2(float x) {
    return __builtin_amdgcn_exp2f(x);
}

// async global->LDS, 16B per lane. LDS dest is wave-uniform base (HW adds lane*16).
__device__ __forceinline__ void gll16(const u16* g, u16* l) {
    __builtin_amdgcn_global_load_lds(
        (const __attribute__((address_space(1))) u32*)(const void*)g,
        (__attribute__((address_space(3))) u32*)(void*)l, 16, 0, 0);
}

// ---------------- fused prep: x->bf16, weight transpose, bias concat ------------------
__device__ __forceinline__ void wt_tile(const float* Wq, const float* Wk, const float* Wv,
                                        u16* Whi, int K, int bx, int by,
                                        float* tile /* [32][33] */) {
    int k0 = by * 32, n0 = bx * 32;
    int tx = threadIdx.x & 31, ty = threadIdx.x >> 5;   // ty in 0..7
#pragma unroll
    for (int i = 0; i < 4; i++) {
        int kk = k0 + ty + i * 8;
        int n  = n0 + tx;
        float v;
        if (n < 1024)      v = Wq[(size_t)kk * 1024 + n];
        else if (n < 1280) v = Wk[(size_t)kk * 256 + (n - 1024)];
        else               v = Wv[(size_t)kk * 256 + (n - 1280)];
        tile[(ty + i * 8) * 33 + tx] = v;
    }
    __syncthreads();
#pragma unroll
    for (int i = 0; i < 4; i++) {
        int nn = n0 + ty + i * 8;      // output row (n)
        int kk = k0 + tx;              // output col (k)
        Whi[(size_t)nn * K + kk] = f2bf(tile[tx * 33 + ty + i * 8]);
    }
}

__global__ __launch_bounds__(256) void prep_all(
    const float* __restrict__ x,
    const float* __restrict__ Wq, const float* __restrict__ Wk, const float* __restrict__ Wv,
    const float* __restrict__ Wo,
    const float* __restrict__ bq, const float* __restrict__ bk, const float* __restrict__ bv,
    u16* __restrict__ xhi, u16* __restrict__ Wqkvh,
    u16* __restrict__ Woh, float* __restrict__ bqkv) {
    __shared__ float tile[32 * 33];
    int blk = blockIdx.x;
    if (blk < 4096) {                          // x fp32 -> bf16 (4 elems/thread)
        int i = blk * 256 + threadIdx.x;
        f32x4 v = *(const f32x4*)(x + (size_t)i * 4);
        u16x4 h;
#pragma unroll
        for (int j = 0; j < 4; j++) h[j] = f2bf(v[j]);
        *(u16x4*)(xhi + (size_t)i * 4) = h;
    } else if (blk < 4096 + 1536) {            // Wqkv^T hi (48 x 32 tiles)
        int id = blk - 4096;
        wt_tile(Wq, Wk, Wv, Wqkvh, 1024, id % 48, id / 48, tile);
    } else if (blk < 4096 + 1536 + 1024) {     // Wo^T hi (32 x 32 tiles)
        int id = blk - (4096 + 1536);
        wt_tile(Wo, Wo, Wo, Woh, 1024, id % 32, id / 32, tile);
    } else {                                   // bias concat
#pragma unroll
        for (int base = 0; base < 1536; base += 256) {
            int i = base + threadIdx.x;
            bqkv[i] = (i < 1024) ? bq[i] : ((i < 1280) ? bk[i - 1024] : bv[i - 1280]);
        }
    }
}

// ---------------- GEMM, 2-phase pipelined staging, 8 waves, single-bf16 ---------------
// C[M][N] = A @ B^T + bias.  Bt[N][K].  Tile 128 x 64, EIGHT waves (4x2), each wave a
// 32x32 quadrant (2x2 of 16x16x32 MFMA).  (Single-term OP gemm: attn output sigma~0.02
// => split-precision contribution ~1e-5, 25x under threshold — R23 audit, R23-proven.)
// MODE 0: write C fp32. MODE 1: fused QKV epilogue -> Qb(*0.125*log2e), Kb,
//         and V written DIRECTLY to Vtp (transposed + key-permuted).
template<int MODE>
__global__ __launch_bounds__(512) void gemm_2ph(
    const u16* __restrict__ Ahi, const u16* __restrict__ Bhi,
    const float* __restrict__ bias, float* __restrict__ C,
    u16* __restrict__ Qb, u16* __restrict__ Kb, u16* __restrict__ Vtp,
    int M, int N, int K) {
    __shared__ __align__(16) u16 sA[2][128 * 32];
    __shared__ __align__(16) u16 sB[2][64 * 32];
    int tid = threadIdx.x;
    int lane = tid & 63;
    int wv = tid >> 6;                                  // 0..7
    int m0 = blockIdx.y * 128, n0 = blockIdx.x * 64;
    int wm = (wv >> 1) * 32, wn = (wv & 1) * 32;
    int lr = lane & 15, lg = lane >> 4;

    f32x4 acc[2][2];
#pragma unroll
    for (int a = 0; a < 2; a++)
#pragma unroll
        for (int b = 0; b < 2; b++) acc[a][b] = (f32x4){0.f, 0.f, 0.f, 0.f};

    // A staging: wave wv covers rows wv*16..+15 (slot = lane: row lane>>2, chunk lane&3)
    int rl = wv * 16 + (lane >> 2);                     // 0..127
    int jl = (((lane & 3) ^ ((rl >> 1) & 3)) * 8);      // pre-swizzled source chunk
    size_t aoff = (size_t)(m0 + rl) * K + jl;
    // B staging: waves 0-3 cover rows 0..63
    int brl = (wv & 3) * 16 + (lane >> 2);              // 0..63
    int bjl = (((lane & 3) ^ ((brl >> 1) & 3)) * 8);
    size_t boff = (size_t)(n0 + brl) * K + bjl;

    auto STAGE = [&](int buf, int k0) {
        gll16(Ahi + aoff + k0, &sA[buf][0] + wv * 512);
        if (wv < 4) gll16(Bhi + boff + k0, &sB[buf][0] + (wv & 3) * 512);
    };

    STAGE(0, 0);
    int nit = K >> 5;
    for (int it = 0; it < nit; ++it) {
        int cur = it & 1;
        if (it + 1 < nit) {
            STAGE(cur ^ 1, (it + 1) * 32);             // next tile in flight during compute
            if (wv < 4) asm volatile("s_waitcnt vmcnt(2)" ::: "memory");
            else        asm volatile("s_waitcnt vmcnt(1)" ::: "memory");
        } else {
            asm volatile("s_waitcnt vmcnt(0)" ::: "memory");
        }
        __builtin_amdgcn_s_barrier();
        asm volatile("" ::: "memory");

        bf16x8 af[2], bfr[2];
#pragma unroll
        for (int ms = 0; ms < 2; ms++) {
            int row = wm + ms * 16 + lr;
            af[ms] = *(const bf16x8*)&sA[cur][row * 32 + (lg ^ ((row >> 1) & 3)) * 8];
        }
#pragma unroll
        for (int ns = 0; ns < 2; ns++) {
            int row = wn + ns * 16 + lr;
            bfr[ns] = *(const bf16x8*)&sB[cur][row * 32 + (lg ^ ((row >> 1) & 3)) * 8];
        }
        __builtin_amdgcn_s_setprio(1);
#pragma unroll
        for (int ms = 0; ms < 2; ms++)
#pragma unroll
            for (int ns = 0; ns < 2; ns++)
                acc[ms][ns] = __builtin_amdgcn_mfma_f32_16x16x32_bf16(af[ms], bfr[ns], acc[ms][ns], 0, 0, 0);
        __builtin_amdgcn_s_setprio(0);
        __builtin_amdgcn_s_barrier();   // all reads of cur done before it is restaged
    }

    int rq = lg * 4;
#pragma unroll
    for (int ns = 0; ns < 2; ns++) {
        int n = n0 + wn + ns * 16 + lr;
        float bvv = bias[n];
#pragma unroll
        for (int ms = 0; ms < 2; ms++) {
            int mbase = m0 + wm + ms * 16 + rq;
#pragma unroll
            for (int r = 0; r < 4; r++) {
                float val = acc[ms][ns][r] + bvv;
                int m = mbase + r;
                if (MODE == 0) {
                    C[(size_t)m * N + n] = val;
                } else {
                    if (n < 1024)      Qb[(size_t)m * 1024 + n] = f2bf(val * 0.1803368801f);
                    else if (n < 1280) Kb[(size_t)m * 256 + (n - 1024)] = f2bf(val);
                    else {
                        // direct transposed + key-permuted V write (replaces prep_vt):
                        // p(ti) inverts attn's ti(p)=((p&1)<<4)|((p>>1)&15)|(p&32)
                        int dh6 = n - 1280;                 // 0..255
                        int g = dh6 >> 6, dh = dh6 & 63;
                        int bb = m >> 11, tok = m & 2047;
                        int ti = tok & 63;
                        int p = ((ti >> 4) & 1) | ((ti & 15) << 1) | (ti & 32);
                        Vtp[((size_t)((bb * 4 + g) * 64 + dh)) * 2048 + (tok & ~63) + p]
                            = f2bf(val);
                    }
                }
            }
        }
    }
}

// ---------------- flash attention (R23-proven, ~67.5us — byte-identical) --------------
// 4 waves x 32 q-rows, 512 blocks; (b,g) in LOW 3 bid bits (XCD-local KV streams);
// triple-buffered K/V via global_load_lds, ONE barrier/iter; chunk-XOR swizzle;
// no-max exp2 softmax (Q pre-scaled by 0.125*log2e), deferred denominator;
// pack via v_cvt_pk (compiler); setprio around MFMA clusters; O single bf16.
__global__ __launch_bounds__(256) void attn_kernel(
    const u16* __restrict__ Qb, const u16* __restrict__ Kb,
    const u16* __restrict__ Vtp, u16* __restrict__ Ohi) {
    __shared__ __align__(16) u16 sK[3][4096];
    __shared__ __align__(16) u16 sV[3][4096];
    __shared__ __align__(16) u16 sP[4][32 * 72];

    const int tid = threadIdx.x;
    const int wv = tid >> 6, lane = tid & 63;
    const int lr = lane & 15, lg = lane >> 4;

    const int bid = blockIdx.x;
    const int b  = bid & 1;                  // (b,g) in LOW 3 bits -> XCD-local KV stream
    const int g  = (bid >> 1) & 3;
    const int h  = g * 4 + ((bid >> 3) & 3);
    const int tc = (bid >> 5) & 15;
    const int tok0 = tc * 128 + wv * 32;

    // Q A-fragments: 2 m-tiles x 2 k-steps
    bf16x8 qf[2][2];
#pragma unroll
    for (int mm = 0; mm < 2; mm++) {
        const u16* qrow = Qb + (size_t)(b * 2048 + tok0 + mm * 16 + lr) * 1024 + h * 64 + lg * 8;
        qf[mm][0] = *(const bf16x8*)(qrow);
        qf[mm][1] = *(const bf16x8*)(qrow + 32);
    }

    // staging: wave covers rows wv*16..+15 (2 issues of 8 rows), swizzled source chunk
    const int srow = wv * 16 + (lane >> 3);
    const int sjj  = (lane & 7) ^ (srow & 7);
    const u16* kgb = Kb  + (size_t)(b * 2048 + srow) * 256 + g * 64 + sjj * 8;
    const u16* vgb = Vtp + (size_t)((b * 4 + g) * 64 + srow) * 2048 + sjj * 8;

    f32x4 o_[2][4];
    float ls[2][4];
#pragma unroll
    for (int mm = 0; mm < 2; mm++)
#pragma unroll
        for (int r = 0; r < 4; r++) { o_[mm][r] = (f32x4){0.f, 0.f, 0.f, 0.f}; ls[mm][r] = 0.f; }

    // prologue: stage tile 0 into buffer 0
    gll16(kgb,         &sK[0][0] + wv * 1024);
    gll16(kgb + 2048,  &sK[0][0] + wv * 1024 + 512);
    gll16(vgb,         &sV[0][0] + wv * 1024);
    gll16(vgb + 16384, &sV[0][0] + wv * 1024 + 512);

    int bufn = 0;                        // buffer holding tile `it` (cycles 0,1,2)
    for (int it = 0; it < 32; ++it) {
        if (it < 31) {
            int nb = bufn + 1; if (nb == 3) nb = 0;
            const u16* kp = kgb + (size_t)(it + 1) * 16384;
            const u16* vp = vgb + (size_t)(it + 1) * 64;
            u16* kd = &sK[nb][0] + wv * 1024;
            u16* vd = &sV[nb][0] + wv * 1024;
            gll16(kp,         kd);
            gll16(kp + 2048,  kd + 512);
            gll16(vp,         vd);
            gll16(vp + 16384, vd + 512);
            asm volatile("s_waitcnt vmcnt(4)" ::: "memory");   // cur landed, next 4 in flight
        } else {
            asm volatile("s_waitcnt vmcnt(0)" ::: "memory");
        }
        __builtin_amdgcn_s_barrier();    // ONE barrier per iter (R19-proven ledger)

        const u16* kt = &sK[bufn][0];
        const u16* vt = &sV[bufn][0];

        // K fragments (shared across m-tiles)
        bf16x8 kf0[4], kf1[4];
#pragma unroll
        for (int t = 0; t < 4; t++) {
            int row = t * 16 + lr;
            kf0[t] = *(const bf16x8*)(kt + (row * 8 + (lg ^ (row & 7))) * 8);
            kf1[t] = *(const bf16x8*)(kt + (row * 8 + ((4 + lg) ^ (row & 7))) * 8);
        }
        // S = Q @ K^T (exp2 domain)
        f32x4 s[2][4];
        __builtin_amdgcn_s_setprio(1);
#pragma unroll
        for (int mm = 0; mm < 2; mm++)
#pragma unroll
            for (int t = 0; t < 4; t++) {
                f32x4 sc = (f32x4){0.f, 0.f, 0.f, 0.f};
                sc = __builtin_amdgcn_mfma_f32_16x16x32_bf16(qf[mm][0], kf0[t], sc, 0, 0, 0);
                sc = __builtin_amdgcn_mfma_f32_16x16x32_bf16(qf[mm][1], kf1[t], sc, 0, 0, 0);
                s[mm][t] = sc;
            }
        __builtin_amdgcn_s_setprio(0);

        // P = exp2(S); accumulate denominator per-lane; pack pairs -> LDS
        u16* sPw = &sP[wv][0];
#pragma unroll
        for (int mm = 0; mm < 2; mm++)
#pragma unroll
            for (int r = 0; r < 4; r++) {
                float p0 = fexp2(s[mm][0][r]);
                float p1 = fexp2(s[mm][1][r]);
                float p2 = fexp2(s[mm][2][r]);
                float p3 = fexp2(s[mm][3][r]);
                ls[mm][r] += (p0 + p1) + (p2 + p3);
                u32 w0 = pack2bf(p0, p1);        // positions 2lr,2lr+1 = keys lr,16+lr
                u32 w1 = pack2bf(p2, p3);        // positions 32+2lr,.. = keys 32+lr,48+lr
                int rowo = (mm * 16 + lg * 4 + r) * 72;
                *(u32*)(sPw + rowo + lr * 2)      = w0;
                *(u32*)(sPw + rowo + 32 + lr * 2) = w1;
            }
        asm volatile("s_waitcnt lgkmcnt(0)" ::: "memory");
        __builtin_amdgcn_sched_barrier(0);

        // O += P @ V  (V tile is key-permuted to match P's packed positions)
        __builtin_amdgcn_s_setprio(1);
#pragma unroll
        for (int ks = 0; ks < 2; ks++) {
            bf16x8 vf[4];
#pragma unroll
            for (int n = 0; n < 4; n++) {
                int row = n * 16 + lr;
                vf[n] = *(const bf16x8*)(vt + (row * 8 + ((ks * 4 + lg) ^ (row & 7))) * 8);
            }
#pragma unroll
            for (int mm = 0; mm < 2; mm++) {
                bf16x8 pa = *(const bf16x8*)(sPw + (mm * 16 + lr) * 72 + ks * 32 + lg * 8);
#pragma unroll
                for (int n = 0; n < 4; n++)
                    o_[mm][n] = __builtin_amdgcn_mfma_f32_16x16x32_bf16(pa, vf[n], o_[mm][n], 0, 0, 0);
            }
        }
        __builtin_amdgcn_s_setprio(0);
        bufn = bufn + 1; if (bufn == 3) bufn = 0;
    }

    // deferred denominator reduce + normalize + bf16 write (single term)
#pragma unroll
    for (int mm = 0; mm < 2; mm++)
#pragma unroll
        for (int r = 0; r < 4; r++) {
            float l = ls[mm][r];
#pragma unroll
            for (int off = 1; off < 16; off <<= 1) l += __shfl_xor(l, off, 64);
            float inv = 1.f / l;
            int row = b * 2048 + tok0 + mm * 16 + lg * 4 + r;
#pragma unroll
            for (int n = 0; n < 4; n++) {
                size_t idx = (size_t)row * 1024 + h * 64 + n * 16 + lr;
                Ohi[idx] = f2bf(o_[mm][n][r] * inv);
            }
        }
}

// ---------------- launch (4 dispatches) ----------------
extern "C" void kernel_launch(void* const* d_in, const int* in_sizes, int n_in,
                              void* d_out, int out_size, void* d_ws, size_t ws_size,
                              hipStream_t stream) {
    const float* x   = (const float*)d_in[0];
    const float* W_q = (const float*)d_in[1];
    const float* b_q = (const float*)d_in[2];
    const float* W_k = (const float*)d_in[3];
    const float* b_k = (const float*)d_in[4];
    const float* W_v = (const float*)d_in[5];
    const float* b_v = (const float*)d_in[6];
    const float* W_o = (const float*)d_in[7];
    const float* b_o = (const float*)d_in[8];
    float* out = (float*)d_out;

    char* ws = (char*)d_ws;
    u16*   xhi   = (u16*)(ws + 0);            //  8 MB  [4096][1024]
    u16*   Wqkvh = (u16*)(ws + 8388608);      //  3 MB  [1536][1024]
    float* bqkv  = (float*)(ws + 11534336);   //  6 KB
    u16*   Qb    = (u16*)(ws + 11540480);     //  8 MB  [4096][1024] (pre-scaled)
    u16*   Kb    = (u16*)(ws + 19929088);     //  2 MB  [4096][256]
    u16*   Vtp   = (u16*)(ws + 22026240);     //  2 MB  [8][64][2048] key-permuted
    u16*   Woh   = (u16*)(ws + 24123392);     //  2 MB  [1024][1024]
    u16*   Ahi   = (u16*)(ws + 26220544);     //  8 MB  attn-out bf16 (ends 34,609,152)

    prep_all<<<6657, 256, 0, stream>>>(x, W_q, W_k, W_v, W_o, b_q, b_k, b_v,
                                       xhi, Wqkvh, Woh, bqkv);
    gemm_2ph<1><<<dim3(24, 32), 512, 0, stream>>>(xhi, Wqkvh, bqkv,
                                                  nullptr, Qb, Kb, Vtp, 4096, 1536, 1024);
    attn_kernel<<<512, 256, 0, stream>>>(Qb, Kb, Vtp, Ahi);
    gemm_2ph<0><<<dim3(16, 32), 512, 0, stream>>>(Ahi, Woh, b_o, out,
                                                  nullptr, nullptr, nullptr, 4096, 1024, 1024);
}